// Round 9
// baseline (239.408 us; speedup 1.0000x reference)
//
#include <hip/hip_runtime.h>
#include <hip/hip_bf16.h>

// GraphQNetwork: 2x GCNConv (9->32->64, relu) + global mean pool + station MLP.
// Round 8: serialization attack. k_gsort = single-pass scatter into per-(g,tile)
// 64B cells (no sort, 2 barriers). k_fused = TPB 512, 13 barriers: single-wave
// shfl scans, self-zeroing M-build (no zero phases), CELL=32 shift/mask parse.

#define NNODES 262144
#define NPG 256
#define NGRAPHS 1024
#define NEDGES 2097152
#define NFEAT 9
#define ECAP2 2560
#define T_EDGES 8192
#define NTILES (NEDGES / T_EDGES)   // 256
#define CELL 32              // u16/cell: [0]=cnt, [1..31]=edges; 64 B = 1 line
#define GSTRIDE (NTILES * CELL)     // 8192 u16 per graph
#define TPB 512

typedef __hip_bfloat16 bf16;
typedef short short8 __attribute__((ext_vector_type(8)));
typedef float f32x4 __attribute__((ext_vector_type(4)));

__device__ __forceinline__ float bfbits(unsigned short u) { return __uint_as_float(((unsigned)u) << 16); }
__device__ __forceinline__ unsigned short f2bbits(float v) { bf16 b = __float2bfloat16(v); return *(unsigned short*)&b; }

// ---- edge partition: direct scatter into deterministic cells ----------------

__global__ void __launch_bounds__(512) k_gsort(const int* __restrict__ src,
                                               const int* __restrict__ dst,
                                               unsigned short* __restrict__ gout) {
    __shared__ int h[NGRAPHS];
    int t = threadIdx.x;
    int base = blockIdx.x * T_EDGES;
    int tile32 = blockIdx.x * CELL;
    h[t] = 0; h[t + 512] = 0;
    __syncthreads();
#pragma unroll 4
    for (int k = 0; k < T_EDGES / 512; ++k) {
        int i = base + k * 512 + t;
        int d = dst[i], s0 = src[i];
        int g = d >> 8;
        int pos = atomicAdd(&h[g], 1);
        if (pos < CELL - 1)
            gout[(size_t)g * GSTRIDE + tile32 + 1 + pos] =
                (unsigned short)(((d & 255) << 8) | (s0 & 255));
    }
    __syncthreads();
    gout[(size_t)t * GSTRIDE + tile32] = (unsigned short)min(h[t], CELL - 1);
    gout[(size_t)(t + 512) * GSTRIDE + tile32] = (unsigned short)min(h[t + 512], CELL - 1);
}

// ---- fused per-graph kernel -------------------------------------------------

__global__ void __launch_bounds__(TPB) k_fused(
    const float* __restrict__ x, const int* __restrict__ station_ids,
    const float* __restrict__ W1, const float* __restrict__ b1,
    const float* __restrict__ W2, const float* __restrict__ b2,
    const float* __restrict__ fc1W, const float* __restrict__ fc1b,
    const float* __restrict__ fc2W, const float* __restrict__ fc2b,
    const unsigned short* __restrict__ gedges, float* __restrict__ out) {

    __shared__ __align__(16) unsigned char Ms[65536];     // half-M: 128 rows x 512 B
    __shared__ __align__(16) unsigned char BufA[16896];   // G1T [32][264] -> fc1s16
    __shared__ __align__(16) unsigned char BufB[16896];   // H1T [32][264]
    __shared__ __align__(16) unsigned char BufC[25600];   // xsf(9216)+EPa(16384) -> S2 [256][40]
    __shared__ __align__(16) unsigned short W2Ts[64 * 40]; // [o][k] stride 40
    __shared__ float W1s[288];
    __shared__ float dinvs[256];
    __shared__ unsigned short Rl[260];
    __shared__ unsigned char El[ECAP2];
    __shared__ unsigned int sru[512];                     // hist bins + cursors
    __shared__ float sts[512];
    __shared__ float meanf[64];
    __shared__ float poolf[64];
    __shared__ unsigned char stmap[256];
    __shared__ float b1s[32], b2s[64], fc1bs[64], fc2ws[64];
    __shared__ int stids[8];
    __shared__ float fc2bv;

    int t = threadIdx.x;
    int g = blockIdx.x;
    int nbase = g * NPG;
    int lane = t & 63, wvid = t >> 6;                     // 8 waves
    int m = lane & 15, quad = lane >> 4;

    float* xsf = (float*)BufC;                            // [256][9] f32
    unsigned short* EPa = (unsigned short*)(BufC + 9216); // cells, 8192 u16
    unsigned short* G1T = (unsigned short*)BufA;          // [32ch][264]
    unsigned short* H1T = (unsigned short*)BufB;          // [32ch][264]
    unsigned short* S2 = (unsigned short*)BufC;           // [256][40]
    unsigned short* fc1s16 = (unsigned short*)BufA;       // [128][64]

    // ---- P0: stage
    {
        const uint4* gev = (const uint4*)(gedges + (size_t)g * GSTRIDE);
        uint4* epv = (uint4*)EPa;
        for (int i = t; i < 2048; i += TPB) epv[i] = gev[i];
    }
    const float* xg = x + (size_t)nbase * NFEAT;
    for (int i = t; i < NPG * NFEAT; i += TPB) xsf[i] = xg[i];
    for (int i = t; i < NFEAT * 32; i += TPB) W1s[i] = W1[i];
    for (int i = t; i < 2048; i += TPB)
        W2Ts[(i >> 5) * 40 + (i & 31)] = f2bbits(W2[(i & 31) * 64 + (i >> 5)]);
    if (t < 32) b1s[t] = b1[t];
    if (t < 64) { b2s[t] = b2[t]; fc1bs[t] = fc1b[t]; fc2ws[t] = fc2W[t]; poolf[t] = 0.f; }
    if (t < 8) stids[t] = station_ids[t];
    if (t == 0) fc2bv = fc2b[0];
    if (t < 256) { stmap[t] = 255; sru[t] = 0u; }
    __syncthreads();                                      // B1
    if (t < 8) stmap[stids[t] & 255] = (unsigned char)t;

    // ---- P1: t<256 lin1 -> G1T; t>=256 dst-histogram over cells
    if (t < 256) {
        int n = t;
        float xv[NFEAT];
#pragma unroll
        for (int k = 0; k < NFEAT; k++) xv[k] = xsf[n * NFEAT + k];
#pragma unroll 4
        for (int c = 0; c < 32; c++) {
            float acc = 0.f;
#pragma unroll
            for (int k = 0; k < NFEAT; k++) acc += xv[k] * W1s[k * 32 + c];
            G1T[c * 264 + n] = f2bbits(acc);
        }
    } else {
        for (int i = t - 256; i < GSTRIDE; i += 256) {
            int p = i & 31;
            if (p) {
                unsigned cnt = EPa[i & ~31];
                if ((unsigned)p <= cnt) atomicAdd(&sru[EPa[i] >> 8], 1u);
            }
        }
    }
    __syncthreads();                                      // B2

    // ---- P2: single-wave scan of 256 bins (4/lane) -> Rl, cursors, dinvs
    if (wvid == 0) {
        int b0 = sru[lane * 4], b1v = sru[lane * 4 + 1], b2v = sru[lane * 4 + 2], b3 = sru[lane * 4 + 3];
        int s = b0 + b1v + b2v + b3;
        int inc = s;
        for (int off = 1; off < 64; off <<= 1) {
            int y = __shfl_up(inc, off);
            if (lane >= off) inc += y;
        }
        int run = inc - s;
        Rl[lane * 4] = (unsigned short)run; sru[256 + lane * 4] = run;
        dinvs[lane * 4] = rsqrtf((float)(b0 + 1)); run += b0;
        Rl[lane * 4 + 1] = (unsigned short)run; sru[257 + lane * 4] = run;
        dinvs[lane * 4 + 1] = rsqrtf((float)(b1v + 1)); run += b1v;
        Rl[lane * 4 + 2] = (unsigned short)run; sru[258 + lane * 4] = run;
        dinvs[lane * 4 + 2] = rsqrtf((float)(b2v + 1)); run += b2v;
        Rl[lane * 4 + 3] = (unsigned short)run; sru[259 + lane * 4] = run;
        dinvs[lane * 4 + 3] = rsqrtf((float)(b3 + 1));
        if (lane == 63) Rl[256] = (unsigned short)inc;
    }
    __syncthreads();                                      // B3

    // ---- P3: scatter edges -> El (dst-sorted src locals)
    for (int i = t; i < GSTRIDE; i += TPB) {
        int p = i & 31;
        if (p) {
            unsigned cnt = EPa[i & ~31];
            if ((unsigned)p <= cnt) {
                unsigned short v = EPa[i];
                unsigned pos = atomicAdd(&sru[256 + (v >> 8)], 1u);
                if (pos < ECAP2) El[pos] = (unsigned char)(v & 255);
            }
        }
    }
    __syncthreads();                                      // B4

    // ---- M-build macro: 4 thr/row, self-zeroing 128B swizzle region
#define BUILD_M(DBASE)                                                          \
    {                                                                           \
        int dl = t >> 2, q = t & 3;                                             \
        int d = (DBASE) + dl;                                                   \
        int zq = q ^ ((d >> 3) & 1);                                            \
        uint4* zp = (uint4*)(Ms + dl * 512 + zq * 128);                         \
        uint4 z = {0u, 0u, 0u, 0u};                                             \
        zp[0] = z; zp[1] = z; zp[2] = z; zp[3] = z;                             \
        zp[4] = z; zp[5] = z; zp[6] = z; zp[7] = z;                             \
        float did = dinvs[d];                                                   \
        if ((d & 255) >> 6 == q) {                                              \
            int sd = d & 255;                                                   \
            *(unsigned short*)(Ms + dl * 512 + (((sd >> 3) ^ (d & 15)) * 16) + (sd & 7) * 2) \
                = f2bbits(did * did);                                           \
        }                                                                       \
        int r0 = Rl[d & 255], r1 = Rl[(d & 255) + 1];                           \
        for (int e = r0; e < r1; ++e) {                                         \
            int s = El[e];                                                      \
            if ((s >> 6) == q) {                                                \
                unsigned short* p =                                             \
                    (unsigned short*)(Ms + dl * 512 + (((s >> 3) ^ (d & 15)) * 16) + (s & 7) * 2); \
                *p = f2bbits(bfbits(*p) + did * dinvs[s]);                      \
            }                                                                   \
        }                                                                       \
    }

    // wait: self-loop diag needs s=d local; for h0 d<128, for h1 d in [128,256)
    // (d&255)>>6 == q picks the owning quadrant of s=d. Handled above.

    // ---- P4: build M(h0)
    BUILD_M(0)
    __syncthreads();                                      // B5

    // ---- P5: agg1(h0) -> H1T nodes 0..127 (wave w: mt=w, nt 0..1)
    {
        f32x4 acc[2] = {};
        for (int kt = 0; kt < 8; ++kt) {
            short8 af = *(const short8*)(Ms + (wvid * 16 + m) * 512 + (((kt * 4 + quad) ^ m) * 16));
            short8 bf0 = *(const short8*)(BufA + (size_t)m * 528 + kt * 64 + quad * 16);
            short8 bf1 = *(const short8*)(BufA + (size_t)(16 + m) * 528 + kt * 64 + quad * 16);
            acc[0] = __builtin_amdgcn_mfma_f32_16x16x32_bf16(af, bf0, acc[0], 0, 0, 0);
            acc[1] = __builtin_amdgcn_mfma_f32_16x16x32_bf16(af, bf1, acc[1], 0, 0, 0);
        }
#pragma unroll
        for (int ni = 0; ni < 2; ++ni) {
            int ch = ni * 16 + m;
            float bb = b1s[ch];
#pragma unroll
            for (int r = 0; r < 4; ++r) {
                int node = wvid * 16 + quad * 4 + r;
                H1T[ch * 264 + node] = f2bbits(fmaxf(acc[ni][r] + bb, 0.f));
            }
        }
    }
    __syncthreads();                                      // B6

    // ---- P6: build M(h1)
    BUILD_M(128)
    __syncthreads();                                      // B7

    // ---- P7: agg1(h1) -> H1T nodes 128..255
    {
        f32x4 acc[2] = {};
        for (int kt = 0; kt < 8; ++kt) {
            short8 af = *(const short8*)(Ms + (wvid * 16 + m) * 512 + (((kt * 4 + quad) ^ m) * 16));
            short8 bf0 = *(const short8*)(BufA + (size_t)m * 528 + kt * 64 + quad * 16);
            short8 bf1 = *(const short8*)(BufA + (size_t)(16 + m) * 528 + kt * 64 + quad * 16);
            acc[0] = __builtin_amdgcn_mfma_f32_16x16x32_bf16(af, bf0, acc[0], 0, 0, 0);
            acc[1] = __builtin_amdgcn_mfma_f32_16x16x32_bf16(af, bf1, acc[1], 0, 0, 0);
        }
#pragma unroll
        for (int ni = 0; ni < 2; ++ni) {
            int ch = ni * 16 + m;
            float bb = b1s[ch];
#pragma unroll
            for (int r = 0; r < 4; ++r) {
                int node = 128 + wvid * 16 + quad * 4 + r;
                H1T[ch * 264 + node] = f2bbits(fmaxf(acc[ni][r] + bb, 0.f));
            }
        }
    }
    __syncthreads();                                      // B8

    // ---- P8: fc1 stage (over G1T) + agg2'(h1) [M(h1) resident] -> S2 rows 128..255
    for (int i = t; i < 8192; i += TPB) fc1s16[i] = f2bbits(fc1W[i]);
    {
        f32x4 acc[2] = {};
        for (int kt = 0; kt < 8; ++kt) {
            short8 af = *(const short8*)(Ms + (wvid * 16 + m) * 512 + (((kt * 4 + quad) ^ m) * 16));
            short8 bf0 = *(const short8*)(BufB + (size_t)m * 528 + kt * 64 + quad * 16);
            short8 bf1 = *(const short8*)(BufB + (size_t)(16 + m) * 528 + kt * 64 + quad * 16);
            acc[0] = __builtin_amdgcn_mfma_f32_16x16x32_bf16(af, bf0, acc[0], 0, 0, 0);
            acc[1] = __builtin_amdgcn_mfma_f32_16x16x32_bf16(af, bf1, acc[1], 0, 0, 0);
        }
#pragma unroll
        for (int ni = 0; ni < 2; ++ni) {
            int ch = ni * 16 + m;
#pragma unroll
            for (int r = 0; r < 4; ++r) {
                int node = 128 + wvid * 16 + quad * 4 + r;
                S2[node * 40 + ch] = f2bbits(acc[ni][r]);
            }
        }
    }
    __syncthreads();                                      // B9

    // ---- P9: rebuild M(h0)
    BUILD_M(0)
    __syncthreads();                                      // B10

    // ---- P10: agg2'(h0) -> S2 rows 0..127
    {
        f32x4 acc[2] = {};
        for (int kt = 0; kt < 8; ++kt) {
            short8 af = *(const short8*)(Ms + (wvid * 16 + m) * 512 + (((kt * 4 + quad) ^ m) * 16));
            short8 bf0 = *(const short8*)(BufB + (size_t)m * 528 + kt * 64 + quad * 16);
            short8 bf1 = *(const short8*)(BufB + (size_t)(16 + m) * 528 + kt * 64 + quad * 16);
            acc[0] = __builtin_amdgcn_mfma_f32_16x16x32_bf16(af, bf0, acc[0], 0, 0, 0);
            acc[1] = __builtin_amdgcn_mfma_f32_16x16x32_bf16(af, bf1, acc[1], 0, 0, 0);
        }
#pragma unroll
        for (int ni = 0; ni < 2; ++ni) {
            int ch = ni * 16 + m;
#pragma unroll
            for (int r = 0; r < 4; ++r) {
                int node = wvid * 16 + quad * 4 + r;
                S2[node * 40 + ch] = f2bbits(acc[ni][r]);
            }
        }
    }
    __syncthreads();                                      // B11

    // ---- P11: lin2 = relu(S2@W2+b2); pool + stations from accumulators
    {
#pragma unroll
        for (int mi = 0; mi < 2; ++mi) {
            int mt = wvid * 2 + mi;
            short8 af = *(const short8*)(BufC + (size_t)(mt * 16 + m) * 80 + quad * 16);
#pragma unroll
            for (int ni = 0; ni < 4; ++ni) {
                short8 bf = *(const short8*)((const unsigned char*)W2Ts + (size_t)(ni * 16 + m) * 80 + quad * 16);
                f32x4 c = {};
                c = __builtin_amdgcn_mfma_f32_16x16x32_bf16(af, bf, c, 0, 0, 0);
                int ch = ni * 16 + m;
                float bb = b2s[ch];
                float hv[4];
                float p = 0.f;
#pragma unroll
                for (int r = 0; r < 4; ++r) { hv[r] = fmaxf(c[r] + bb, 0.f); p += hv[r]; }
                p += __shfl_down(p, 32);
                p += __shfl_down(p, 16);
                if (quad == 0) atomicAdd(&poolf[ch], p);
#pragma unroll
                for (int r = 0; r < 4; ++r) {
                    int node = mt * 16 + quad * 4 + r;
                    int si = stmap[node];
                    if (si != 255) sts[si * 64 + ch] = hv[r];
                }
            }
        }
    }
    __syncthreads();                                      // B12

    // ---- P12: mean
    if (t < 64) meanf[t] = poolf[t] * (1.0f / 256.0f);
    __syncthreads();                                      // B13

    // ---- P13: MLP, one wave per station
    {
        int l = lane;
        int si = wvid;
        const float* st = sts + si * 64;
        float acc = 0.f;
#pragma unroll 8
        for (int k = 0; k < 64; k++) acc += st[k] * bfbits(fc1s16[k * 64 + l]);
#pragma unroll 8
        for (int k = 0; k < 64; k++) acc += meanf[k] * bfbits(fc1s16[(64 + k) * 64 + l]);
        float a = fmaxf(acc + fc1bs[l], 0.f) * fc2ws[l];
        for (int off = 32; off > 0; off >>= 1) a += __shfl_down(a, off);
        if (l == 0) out[g * 8 + si] = a + fc2bv;
    }
#undef BUILD_M
}

// ---- launch -----------------------------------------------------------------

extern "C" void kernel_launch(void* const* d_in, const int* in_sizes, int n_in,
                              void* d_out, int out_size, void* d_ws, size_t ws_size,
                              hipStream_t stream) {
    const float* x = (const float*)d_in[0];
    const int* ei = (const int*)d_in[1];
    const int* station_ids = (const int*)d_in[2];
    const float* W1 = (const float*)d_in[3];
    const float* b1 = (const float*)d_in[4];
    const float* W2 = (const float*)d_in[5];
    const float* bias2 = (const float*)d_in[6];
    const float* fc1W = (const float*)d_in[7];
    const float* fc1b = (const float*)d_in[8];
    const float* fc2W = (const float*)d_in[9];
    const float* fc2b = (const float*)d_in[10];
    float* out = (float*)d_out;
    (void)in_sizes; (void)n_in; (void)out_size; (void)ws_size;

    unsigned short* gout = (unsigned short*)d_ws;   // 1024*8192*2 = 16.8 MB

    const int* esrc = ei;
    const int* edst = ei + NEDGES;

    k_gsort<<<NTILES, 512, 0, stream>>>(esrc, edst, gout);
    k_fused<<<NGRAPHS, TPB, 0, stream>>>(x, station_ids, W1, b1, W2, bias2,
                                         fc1W, fc1b, fc2W, fc2b, gout, out);
}

// Round 10
// 223.687 us; speedup vs baseline: 1.0703x; 1.0703x over previous
//
#include <hip/hip_runtime.h>
#include <hip/hip_bf16.h>

// GraphQNetwork: 2x GCNConv (9->32->64, relu) + global mean pool + station MLP.
// Round 9: r6 fused structure (linear zeros, known-good) + single-wave scans +
// bank-conflict-free strides (266/38, stride mod 32 odd-ish) ; gsort at T=4096,
// grid 512 (2 blocks/CU co-resident), CELL=24 deterministic cells.

#define NNODES 262144
#define NPG 256
#define NGRAPHS 1024
#define NEDGES 2097152
#define NFEAT 9
#define ECAP2 2560
#define T_EDGES 4096
#define NTILES (NEDGES / T_EDGES)   // 512
#define CELL 24              // u16/cell: [0]=cnt, [1..23]=payloads
#define CELLD 23
#define GSTRIDE (NTILES * CELL)     // 12288 u16 per graph
#define TPB 512

typedef __hip_bfloat16 bf16;
typedef short short8 __attribute__((ext_vector_type(8)));
typedef float f32x4 __attribute__((ext_vector_type(4)));

__device__ __forceinline__ float bfbits(unsigned short u) { return __uint_as_float(((unsigned)u) << 16); }
__device__ __forceinline__ unsigned short f2bbits(float v) { bf16 b = __float2bfloat16(v); return *(unsigned short*)&b; }

// ---- edge partition: tile counting sort -> deterministic cells --------------

__global__ void __launch_bounds__(512) k_gsort(const int* __restrict__ src,
                                               const int* __restrict__ dst,
                                               unsigned short* __restrict__ gout) {
    __shared__ unsigned int ed[T_EDGES];     // g<<16 | d8<<8 | s8
    __shared__ unsigned short sp[T_EDGES];
    __shared__ unsigned short bid[T_EDGES];
    __shared__ int cArr[NGRAPHS];            // hist -> cursor
    __shared__ int eArr[NGRAPHS];
    __shared__ int bW[NGRAPHS];
    int t = threadIdx.x;
    int base = blockIdx.x * T_EDGES;
    int tile24 = blockIdx.x * CELL;
    cArr[t] = 0; cArr[t + 512] = 0;
    __syncthreads();
#pragma unroll 4
    for (int k = 0; k < T_EDGES / 512; ++k) {
        int i = base + k * 512 + t;
        int d = dst[i], s0 = src[i];
        int g = d >> 8;
        ed[k * 512 + t] = ((unsigned)g << 16) | ((d & 255) << 8) | (s0 & 255);
        atomicAdd(&cArr[g], 1);
    }
    __syncthreads();
    if (t < 64) {                            // single-wave scan of 1024 bins
        int v[16]; int s = 0;
#pragma unroll
        for (int j = 0; j < 16; ++j) { v[j] = cArr[t * 16 + j]; s += v[j]; }
        int inc = s;
        for (int off = 1; off < 64; off <<= 1) {
            int y = __shfl_up(inc, off);
            if (t >= off) inc += y;
        }
        int run = inc - s;
#pragma unroll
        for (int j = 0; j < 16; ++j) {
            int g = t * 16 + j;
            cArr[g] = run;                   // cursor
            eArr[g] = run;
            bW[g] = g * GSTRIDE + tile24 + 1 - run;
            run += v[j];
        }
    }
    __syncthreads();
#pragma unroll 4
    for (int k = 0; k < T_EDGES / 512; ++k) {
        unsigned v = ed[k * 512 + t];
        int g = v >> 16;
        int pos = atomicAdd(&cArr[g], 1);
        sp[pos] = (unsigned short)(v & 0xFFFF);
        bid[pos] = (unsigned short)g;
    }
    __syncthreads();
#pragma unroll 4
    for (int k = 0; k < T_EDGES / 512; ++k) {
        int i = k * 512 + t;
        int g = bid[i];
        if (i - eArr[g] < CELLD) gout[bW[g] + i] = sp[i];
    }
    {   // inline counts (cursor now = e + cnt)
        int cnt0 = cArr[t] - eArr[t];
        int cnt1 = cArr[t + 512] - eArr[t + 512];
        gout[(size_t)t * GSTRIDE + tile24] = (unsigned short)min(cnt0, CELLD);
        gout[(size_t)(t + 512) * GSTRIDE + tile24] = (unsigned short)min(cnt1, CELLD);
    }
}

// ---- fused per-graph kernel -------------------------------------------------

__global__ void __launch_bounds__(TPB) k_fused(
    const float* __restrict__ x, const int* __restrict__ station_ids,
    const float* __restrict__ W1, const float* __restrict__ b1,
    const float* __restrict__ W2, const float* __restrict__ b2,
    const float* __restrict__ fc1W, const float* __restrict__ fc1b,
    const float* __restrict__ fc2W, const float* __restrict__ fc2b,
    const unsigned short* __restrict__ gedges, float* __restrict__ out) {

    __shared__ __align__(16) unsigned char Ms[65536];     // half-M: 128 x 512 B
    __shared__ __align__(16) unsigned char BufA[17024];   // G1T [32][266] -> fc1s16
    __shared__ __align__(16) unsigned char BufB[17024];   // H1T [32][266]
    __shared__ __align__(16) unsigned char BufC[33792];   // xsf(9216)+EPa(24576) -> S2 [256][38]
    __shared__ __align__(16) unsigned short W2Ts[64 * 40];
    __shared__ float W1s[288];
    __shared__ float dinvs[256];
    __shared__ unsigned short Rl[260];
    __shared__ unsigned char El[ECAP2];
    __shared__ unsigned int sru[512];
    __shared__ float sts[512];
    __shared__ float meanf[64];
    __shared__ float poolf[64];
    __shared__ unsigned char stmap[256];
    __shared__ float b1s[32], b2s[64], fc1bs[64], fc2ws[64];
    __shared__ int stids[8];
    __shared__ float fc2bv;

    int t = threadIdx.x;
    int g = blockIdx.x;
    int nbase = g * NPG;
    int lane = t & 63, wvid = t >> 6;
    int m = lane & 15, quad = lane >> 4;

    float* xsf = (float*)BufC;                            // [256][9] f32
    unsigned short* EPa = (unsigned short*)(BufC + 9216); // cells, 12288 u16
    unsigned short* G1T = (unsigned short*)BufA;          // [32][266]
    unsigned short* H1T = (unsigned short*)BufB;          // [32][266]
    unsigned short* S2 = (unsigned short*)BufC;           // [256][38]
    unsigned short* fc1s16 = (unsigned short*)BufA;       // [128][64]

    // ---- P0: stage + zero Ms (linear, conflict-free)
    {
        const uint4* gev = (const uint4*)(gedges + (size_t)g * GSTRIDE);
        uint4* epv = (uint4*)EPa;
        for (int i = t; i < GSTRIDE / 8; i += TPB) epv[i] = gev[i];
    }
    const float* xg = x + (size_t)nbase * NFEAT;
    for (int i = t; i < NPG * NFEAT; i += TPB) xsf[i] = xg[i];
    for (int i = t; i < NFEAT * 32; i += TPB) W1s[i] = W1[i];
    for (int i = t; i < 2048; i += TPB)
        W2Ts[(i >> 5) * 40 + (i & 31)] = f2bbits(W2[(i & 31) * 64 + (i >> 5)]);
    if (t < 32) b1s[t] = b1[t];
    if (t < 64) { b2s[t] = b2[t]; fc1bs[t] = fc1b[t]; fc2ws[t] = fc2W[t]; poolf[t] = 0.f; }
    if (t < 8) stids[t] = station_ids[t];
    if (t == 0) fc2bv = fc2b[0];
    if (t < 256) { stmap[t] = 255; sru[t] = 0u; }
    {
        uint4* mz = (uint4*)Ms;
        uint4 z = {0u, 0u, 0u, 0u};
        for (int i = t; i < 4096; i += TPB) mz[i] = z;
    }
    __syncthreads();                                      // B1
    if (t < 8) stmap[stids[t] & 255] = (unsigned char)t;

    // ---- P0b: hist over cells
    for (int i = t; i < GSTRIDE; i += TPB) {
        int cell = i / CELL;
        int pos = i - cell * CELL;
        if (pos) {
            unsigned cnt = EPa[cell * CELL];
            if ((unsigned)pos <= cnt) atomicAdd(&sru[EPa[i] >> 8], 1u);
        }
    }
    __syncthreads();                                      // B2

    // ---- P0c: single-wave scan of 256 bins -> Rl, cursors, dinvs
    if (wvid == 0) {
        int b0 = sru[lane * 4], b1v = sru[lane * 4 + 1], b2v = sru[lane * 4 + 2], b3 = sru[lane * 4 + 3];
        int s = b0 + b1v + b2v + b3;
        int inc = s;
        for (int off = 1; off < 64; off <<= 1) {
            int y = __shfl_up(inc, off);
            if (lane >= off) inc += y;
        }
        int run = inc - s;
        Rl[lane * 4] = (unsigned short)run; sru[256 + lane * 4] = run;
        dinvs[lane * 4] = rsqrtf((float)(b0 + 1)); run += b0;
        Rl[lane * 4 + 1] = (unsigned short)run; sru[257 + lane * 4] = run;
        dinvs[lane * 4 + 1] = rsqrtf((float)(b1v + 1)); run += b1v;
        Rl[lane * 4 + 2] = (unsigned short)run; sru[258 + lane * 4] = run;
        dinvs[lane * 4 + 2] = rsqrtf((float)(b2v + 1)); run += b2v;
        Rl[lane * 4 + 3] = (unsigned short)run; sru[259 + lane * 4] = run;
        dinvs[lane * 4 + 3] = rsqrtf((float)(b3 + 1));
        if (lane == 63) Rl[256] = (unsigned short)inc;
    }
    __syncthreads();                                      // B3

    // ---- P0d: scatter -> El
    for (int i = t; i < GSTRIDE; i += TPB) {
        int cell = i / CELL;
        int pos = i - cell * CELL;
        if (pos) {
            unsigned cnt = EPa[cell * CELL];
            if ((unsigned)pos <= cnt) {
                unsigned short v = EPa[i];
                unsigned p = atomicAdd(&sru[256 + (v >> 8)], 1u);
                if (p < ECAP2) El[p] = (unsigned char)(v & 255);
            }
        }
    }
    __syncthreads();                                      // B4

    // ---- P1: t<256 builds M(h0) (2 thr/row); t>=256 lin1 -> G1T (stride 266)
    if (t < 256) {
        int dl = t >> 1, q = t & 1;
        int d = dl;
        float did = dinvs[d];
        if ((d >> 7) == q)
            *(unsigned short*)(Ms + dl * 512 + (((d >> 3) ^ (d & 15)) * 16) + (d & 7) * 2)
                = f2bbits(did * did);
        int r0 = Rl[d], r1 = Rl[d + 1];
        for (int e = r0; e < r1; ++e) {
            int s = El[e];
            if ((s >> 7) == q) {
                unsigned short* p =
                    (unsigned short*)(Ms + dl * 512 + (((s >> 3) ^ (d & 15)) * 16) + (s & 7) * 2);
                *p = f2bbits(bfbits(*p) + did * dinvs[s]);
            }
        }
    } else {
        int n = t - 256;
        float xv[NFEAT];
#pragma unroll
        for (int k = 0; k < NFEAT; k++) xv[k] = xsf[n * NFEAT + k];
#pragma unroll 4
        for (int c = 0; c < 32; c++) {
            float acc = 0.f;
#pragma unroll
            for (int k = 0; k < NFEAT; k++) acc += xv[k] * W1s[k * 32 + c];
            G1T[c * 266 + n] = f2bbits(acc);
        }
    }
    __syncthreads();                                      // B5

    // ---- P2: agg1(h0) -> H1T nodes 0..127
    {
        f32x4 acc[2] = {};
        for (int kt = 0; kt < 8; ++kt) {
            short8 af = *(const short8*)(Ms + (wvid * 16 + m) * 512 + (((kt * 4 + quad) ^ m) * 16));
            short8 bf0 = *(const short8*)(BufA + (size_t)m * 532 + kt * 64 + quad * 16);
            short8 bf1 = *(const short8*)(BufA + (size_t)(16 + m) * 532 + kt * 64 + quad * 16);
            acc[0] = __builtin_amdgcn_mfma_f32_16x16x32_bf16(af, bf0, acc[0], 0, 0, 0);
            acc[1] = __builtin_amdgcn_mfma_f32_16x16x32_bf16(af, bf1, acc[1], 0, 0, 0);
        }
#pragma unroll
        for (int ni = 0; ni < 2; ++ni) {
            int ch = ni * 16 + m;
            float bb = b1s[ch];
#pragma unroll
            for (int r = 0; r < 4; ++r) {
                int node = wvid * 16 + quad * 4 + r;
                H1T[ch * 266 + node] = f2bbits(fmaxf(acc[ni][r] + bb, 0.f));
            }
        }
    }
    __syncthreads();                                      // B6

    // ---- P3: zero Ms (linear); build M(h1) (4 thr/row)
    {
        uint4* mz = (uint4*)Ms;
        uint4 z = {0u, 0u, 0u, 0u};
        for (int i = t; i < 4096; i += TPB) mz[i] = z;
    }
    __syncthreads();                                      // B7
    {
        int dl = t >> 2, q = t & 3;
        int d = 128 + dl;
        float did = dinvs[d];
        if (((d & 255) >> 6) == q) {
            int sd = d & 255;
            *(unsigned short*)(Ms + dl * 512 + (((sd >> 3) ^ (d & 15)) * 16) + (sd & 7) * 2)
                = f2bbits(did * did);
        }
        int r0 = Rl[d], r1 = Rl[d + 1];
        for (int e = r0; e < r1; ++e) {
            int s = El[e];
            if ((s >> 6) == q) {
                unsigned short* p =
                    (unsigned short*)(Ms + dl * 512 + (((s >> 3) ^ (d & 15)) * 16) + (s & 7) * 2);
                *p = f2bbits(bfbits(*p) + did * dinvs[s]);
            }
        }
    }
    __syncthreads();                                      // B8

    // ---- P4: agg1(h1) -> H1T nodes 128..255
    {
        f32x4 acc[2] = {};
        for (int kt = 0; kt < 8; ++kt) {
            short8 af = *(const short8*)(Ms + (wvid * 16 + m) * 512 + (((kt * 4 + quad) ^ m) * 16));
            short8 bf0 = *(const short8*)(BufA + (size_t)m * 532 + kt * 64 + quad * 16);
            short8 bf1 = *(const short8*)(BufA + (size_t)(16 + m) * 532 + kt * 64 + quad * 16);
            acc[0] = __builtin_amdgcn_mfma_f32_16x16x32_bf16(af, bf0, acc[0], 0, 0, 0);
            acc[1] = __builtin_amdgcn_mfma_f32_16x16x32_bf16(af, bf1, acc[1], 0, 0, 0);
        }
#pragma unroll
        for (int ni = 0; ni < 2; ++ni) {
            int ch = ni * 16 + m;
            float bb = b1s[ch];
#pragma unroll
            for (int r = 0; r < 4; ++r) {
                int node = 128 + wvid * 16 + quad * 4 + r;
                H1T[ch * 266 + node] = f2bbits(fmaxf(acc[ni][r] + bb, 0.f));
            }
        }
    }
    __syncthreads();                                      // B9

    // ---- P5: fc1 stage (over G1T) + agg2'(h1) -> S2 rows 128..255
    for (int i = t; i < 8192; i += TPB) fc1s16[i] = f2bbits(fc1W[i]);
    {
        f32x4 acc[2] = {};
        for (int kt = 0; kt < 8; ++kt) {
            short8 af = *(const short8*)(Ms + (wvid * 16 + m) * 512 + (((kt * 4 + quad) ^ m) * 16));
            short8 bf0 = *(const short8*)(BufB + (size_t)m * 532 + kt * 64 + quad * 16);
            short8 bf1 = *(const short8*)(BufB + (size_t)(16 + m) * 532 + kt * 64 + quad * 16);
            acc[0] = __builtin_amdgcn_mfma_f32_16x16x32_bf16(af, bf0, acc[0], 0, 0, 0);
            acc[1] = __builtin_amdgcn_mfma_f32_16x16x32_bf16(af, bf1, acc[1], 0, 0, 0);
        }
#pragma unroll
        for (int ni = 0; ni < 2; ++ni) {
            int ch = ni * 16 + m;
#pragma unroll
            for (int r = 0; r < 4; ++r) {
                int node = 128 + wvid * 16 + quad * 4 + r;
                S2[node * 38 + ch] = f2bbits(acc[ni][r]);
            }
        }
    }
    __syncthreads();                                      // B10

    // ---- P6: zero Ms; rebuild M(h0) (4 thr/row)
    {
        uint4* mz = (uint4*)Ms;
        uint4 z = {0u, 0u, 0u, 0u};
        for (int i = t; i < 4096; i += TPB) mz[i] = z;
    }
    __syncthreads();                                      // B11
    {
        int dl = t >> 2, q = t & 3;
        int d = dl;
        float did = dinvs[d];
        if ((d >> 6) == q)
            *(unsigned short*)(Ms + dl * 512 + (((d >> 3) ^ (d & 15)) * 16) + (d & 7) * 2)
                = f2bbits(did * did);
        int r0 = Rl[d], r1 = Rl[d + 1];
        for (int e = r0; e < r1; ++e) {
            int s = El[e];
            if ((s >> 6) == q) {
                unsigned short* p =
                    (unsigned short*)(Ms + dl * 512 + (((s >> 3) ^ (d & 15)) * 16) + (s & 7) * 2);
                *p = f2bbits(bfbits(*p) + did * dinvs[s]);
            }
        }
    }
    __syncthreads();                                      // B12

    // ---- P7: agg2'(h0) -> S2 rows 0..127
    {
        f32x4 acc[2] = {};
        for (int kt = 0; kt < 8; ++kt) {
            short8 af = *(const short8*)(Ms + (wvid * 16 + m) * 512 + (((kt * 4 + quad) ^ m) * 16));
            short8 bf0 = *(const short8*)(BufB + (size_t)m * 532 + kt * 64 + quad * 16);
            short8 bf1 = *(const short8*)(BufB + (size_t)(16 + m) * 532 + kt * 64 + quad * 16);
            acc[0] = __builtin_amdgcn_mfma_f32_16x16x32_bf16(af, bf0, acc[0], 0, 0, 0);
            acc[1] = __builtin_amdgcn_mfma_f32_16x16x32_bf16(af, bf1, acc[1], 0, 0, 0);
        }
#pragma unroll
        for (int ni = 0; ni < 2; ++ni) {
            int ch = ni * 16 + m;
#pragma unroll
            for (int r = 0; r < 4; ++r) {
                int node = wvid * 16 + quad * 4 + r;
                S2[node * 38 + ch] = f2bbits(acc[ni][r]);
            }
        }
    }
    __syncthreads();                                      // B13

    // ---- P8: lin2 = relu(S2@W2+b2); pool + stations from accumulators
    {
#pragma unroll
        for (int mi = 0; mi < 2; ++mi) {
            int mt = wvid * 2 + mi;
            short8 af = *(const short8*)(BufC + (size_t)(mt * 16 + m) * 76 + quad * 16);
#pragma unroll
            for (int ni = 0; ni < 4; ++ni) {
                short8 bf = *(const short8*)((const unsigned char*)W2Ts + (size_t)(ni * 16 + m) * 80 + quad * 16);
                f32x4 c = {};
                c = __builtin_amdgcn_mfma_f32_16x16x32_bf16(af, bf, c, 0, 0, 0);
                int ch = ni * 16 + m;
                float bb = b2s[ch];
                float hv[4];
                float p = 0.f;
#pragma unroll
                for (int r = 0; r < 4; ++r) { hv[r] = fmaxf(c[r] + bb, 0.f); p += hv[r]; }
                p += __shfl_down(p, 32);
                p += __shfl_down(p, 16);
                if (quad == 0) atomicAdd(&poolf[ch], p);
#pragma unroll
                for (int r = 0; r < 4; ++r) {
                    int node = mt * 16 + quad * 4 + r;
                    int si = stmap[node];
                    if (si != 255) sts[si * 64 + ch] = hv[r];
                }
            }
        }
    }
    __syncthreads();                                      // B14

    // ---- P9: mean
    if (t < 64) meanf[t] = poolf[t] * (1.0f / 256.0f);
    __syncthreads();                                      // B15

    // ---- P10: MLP, one wave per station
    {
        int l = lane;
        int si = wvid;
        const float* st = sts + si * 64;
        float acc = 0.f;
#pragma unroll 8
        for (int k = 0; k < 64; k++) acc += st[k] * bfbits(fc1s16[k * 64 + l]);
#pragma unroll 8
        for (int k = 0; k < 64; k++) acc += meanf[k] * bfbits(fc1s16[(64 + k) * 64 + l]);
        float a = fmaxf(acc + fc1bs[l], 0.f) * fc2ws[l];
        for (int off = 32; off > 0; off >>= 1) a += __shfl_down(a, off);
        if (l == 0) out[g * 8 + si] = a + fc2bv;
    }
}

// ---- launch -----------------------------------------------------------------

extern "C" void kernel_launch(void* const* d_in, const int* in_sizes, int n_in,
                              void* d_out, int out_size, void* d_ws, size_t ws_size,
                              hipStream_t stream) {
    const float* x = (const float*)d_in[0];
    const int* ei = (const int*)d_in[1];
    const int* station_ids = (const int*)d_in[2];
    const float* W1 = (const float*)d_in[3];
    const float* b1 = (const float*)d_in[4];
    const float* W2 = (const float*)d_in[5];
    const float* bias2 = (const float*)d_in[6];
    const float* fc1W = (const float*)d_in[7];
    const float* fc1b = (const float*)d_in[8];
    const float* fc2W = (const float*)d_in[9];
    const float* fc2b = (const float*)d_in[10];
    float* out = (float*)d_out;
    (void)in_sizes; (void)n_in; (void)out_size; (void)ws_size;

    unsigned short* gout = (unsigned short*)d_ws;   // 1024*12288*2 = 25.2 MB

    const int* esrc = ei;
    const int* edst = ei + NEDGES;

    k_gsort<<<NTILES, 512, 0, stream>>>(esrc, edst, gout);
    k_fused<<<NGRAPHS, TPB, 0, stream>>>(x, station_ids, W1, b1, W2, bias2,
                                         fc1W, fc1b, fc2W, fc2b, gout, out);
}

// Round 11
// 210.156 us; speedup vs baseline: 1.1392x; 1.0644x over previous
//
#include <hip/hip_runtime.h>
#include <hip/hip_bf16.h>

// GraphQNetwork: 2x GCNConv (9->32->64, relu) + global mean pool + station MLP.
// Round 10: dense per-graph buckets (5 KB, the format fused reads fastest —
// FETCH tracks dur at ~3.4us/MB) + gsort with LINE-CLEAN writes: 64 blocks x
// 32768 edges, runs of ~32 edges (64 B) written whole by one block/XCD.

#define NNODES 262144
#define NPG 256
#define NGRAPHS 1024
#define NEDGES 2097152
#define NFEAT 9
#define ECAP2 2560           // per-graph bucket capacity (mean 2048, sd ~45)
#define T_EDGES 32768
#define NTILES (NEDGES / T_EDGES)   // 64
#define TPB 512

typedef __hip_bfloat16 bf16;
typedef short short8 __attribute__((ext_vector_type(8)));
typedef float f32x4 __attribute__((ext_vector_type(4)));

__device__ __forceinline__ float bfbits(unsigned short u) { return __uint_as_float(((unsigned)u) << 16); }
__device__ __forceinline__ unsigned short f2bbits(float v) { bf16 b = __float2bfloat16(v); return *(unsigned short*)&b; }

// ---- edge partition: big tiles, dense buckets, block-local line writes ------

__global__ void __launch_bounds__(1024) k_gsort(const int* __restrict__ src,
                                                const int* __restrict__ dst,
                                                int* __restrict__ gcur,
                                                unsigned short* __restrict__ gout) {
    __shared__ unsigned short edg[T_EDGES];   // graph id per staged edge
    __shared__ unsigned short pay[T_EDGES];   // d8<<8 | s8
    __shared__ int cnt[NGRAPHS];              // hist -> cursor
    __shared__ int goff[NGRAPHS];             // reserved global run base
    int t = threadIdx.x;
    int base = blockIdx.x * T_EDGES;
    cnt[t] = 0;
    __syncthreads();
    const int4* s4 = (const int4*)(src + base);
    const int4* d4 = (const int4*)(dst + base);
#pragma unroll
    for (int k = 0; k < T_EDGES / 4096; ++k) {
        int idx = k * 1024 + t;
        int4 dv = d4[idx];
        int4 sv = s4[idx];
        int i0 = idx * 4;
        edg[i0]     = (unsigned short)(dv.x >> 8);
        edg[i0 + 1] = (unsigned short)(dv.y >> 8);
        edg[i0 + 2] = (unsigned short)(dv.z >> 8);
        edg[i0 + 3] = (unsigned short)(dv.w >> 8);
        pay[i0]     = (unsigned short)(((dv.x & 255) << 8) | (sv.x & 255));
        pay[i0 + 1] = (unsigned short)(((dv.y & 255) << 8) | (sv.y & 255));
        pay[i0 + 2] = (unsigned short)(((dv.z & 255) << 8) | (sv.z & 255));
        pay[i0 + 3] = (unsigned short)(((dv.w & 255) << 8) | (sv.w & 255));
        atomicAdd(&cnt[dv.x >> 8], 1);
        atomicAdd(&cnt[dv.y >> 8], 1);
        atomicAdd(&cnt[dv.z >> 8], 1);
        atomicAdd(&cnt[dv.w >> 8], 1);
    }
    __syncthreads();
    {   // reserve one dense run per (block, graph); cnt becomes cursor
        int c = cnt[t];
        goff[t] = c ? atomicAdd(&gcur[t], c) : 0;
        cnt[t] = 0;
    }
    __syncthreads();
    for (int i = t; i < T_EDGES; i += 1024) {
        int g = edg[i];
        int pos = atomicAdd(&cnt[g], 1);
        int off = goff[g] + pos;
        if (off < ECAP2) gout[(size_t)g * ECAP2 + off] = pay[i];
    }
}

// ---- fused per-graph kernel -------------------------------------------------

__global__ void __launch_bounds__(TPB) k_fused(
    const float* __restrict__ x, const int* __restrict__ station_ids,
    const float* __restrict__ W1, const float* __restrict__ b1,
    const float* __restrict__ W2, const float* __restrict__ b2,
    const float* __restrict__ fc1W, const float* __restrict__ fc1b,
    const float* __restrict__ fc2W, const float* __restrict__ fc2b,
    const int* __restrict__ gcnt, const unsigned short* __restrict__ gedges,
    float* __restrict__ out) {

    __shared__ __align__(16) unsigned char Ms[65536];     // half-M: 128 x 512 B
    __shared__ __align__(16) unsigned char BufA[17024];   // G1T [32][266] -> fc1s16
    __shared__ __align__(16) unsigned char BufB[17024];   // H1T [32][266]
    __shared__ __align__(16) unsigned char BufC[19456];   // xsf(9216)+EPa(5120) -> S2 [256][38]
    __shared__ __align__(16) unsigned short W2Ts[64 * 40];
    __shared__ float W1s[288];
    __shared__ float dinvs[256];
    __shared__ unsigned short Rl[260];
    __shared__ unsigned char El[ECAP2];
    __shared__ unsigned int sru[512];
    __shared__ float sts[512];
    __shared__ float meanf[64];
    __shared__ float poolf[64];
    __shared__ unsigned char stmap[256];
    __shared__ float b1s[32], b2s[64], fc1bs[64], fc2ws[64];
    __shared__ int stids[8];
    __shared__ float fc2bv;

    int t = threadIdx.x;
    int g = blockIdx.x;
    int nbase = g * NPG;
    int lane = t & 63, wvid = t >> 6;
    int m = lane & 15, quad = lane >> 4;

    float* xsf = (float*)BufC;                            // [256][9] f32
    unsigned short* EPa = (unsigned short*)(BufC + 9216); // dense bucket, 2560 u16
    unsigned short* G1T = (unsigned short*)BufA;          // [32][266]
    unsigned short* H1T = (unsigned short*)BufB;          // [32][266]
    unsigned short* S2 = (unsigned short*)BufC;           // [256][38]
    unsigned short* fc1s16 = (unsigned short*)BufA;       // [128][64]

    // ---- P0: stage + zero Ms (linear)
    int ecnt = min(gcnt[g], ECAP2);
    {
        const uint4* gev = (const uint4*)(gedges + (size_t)g * ECAP2);
        uint4* epv = (uint4*)EPa;
        for (int i = t; i < ECAP2 / 8; i += TPB) epv[i] = gev[i];
    }
    const float* xg = x + (size_t)nbase * NFEAT;
    for (int i = t; i < NPG * NFEAT; i += TPB) xsf[i] = xg[i];
    for (int i = t; i < NFEAT * 32; i += TPB) W1s[i] = W1[i];
    for (int i = t; i < 2048; i += TPB)
        W2Ts[(i >> 5) * 40 + (i & 31)] = f2bbits(W2[(i & 31) * 64 + (i >> 5)]);
    if (t < 32) b1s[t] = b1[t];
    if (t < 64) { b2s[t] = b2[t]; fc1bs[t] = fc1b[t]; fc2ws[t] = fc2W[t]; poolf[t] = 0.f; }
    if (t < 8) stids[t] = station_ids[t];
    if (t == 0) fc2bv = fc2b[0];
    if (t < 256) { stmap[t] = 255; sru[t] = 0u; }
    {
        uint4* mz = (uint4*)Ms;
        uint4 z = {0u, 0u, 0u, 0u};
        for (int i = t; i < 4096; i += TPB) mz[i] = z;
    }
    __syncthreads();                                      // B1
    if (t < 8) stmap[stids[t] & 255] = (unsigned char)t;

    // ---- P0b: dst histogram over dense bucket
    for (int i = t; i < ecnt; i += TPB) atomicAdd(&sru[EPa[i] >> 8], 1u);
    __syncthreads();                                      // B2

    // ---- P0c: single-wave scan -> Rl, cursors, dinvs
    if (wvid == 0) {
        int b0 = sru[lane * 4], b1v = sru[lane * 4 + 1], b2v = sru[lane * 4 + 2], b3 = sru[lane * 4 + 3];
        int s = b0 + b1v + b2v + b3;
        int inc = s;
        for (int off = 1; off < 64; off <<= 1) {
            int y = __shfl_up(inc, off);
            if (lane >= off) inc += y;
        }
        int run = inc - s;
        Rl[lane * 4] = (unsigned short)run; sru[256 + lane * 4] = run;
        dinvs[lane * 4] = rsqrtf((float)(b0 + 1)); run += b0;
        Rl[lane * 4 + 1] = (unsigned short)run; sru[257 + lane * 4] = run;
        dinvs[lane * 4 + 1] = rsqrtf((float)(b1v + 1)); run += b1v;
        Rl[lane * 4 + 2] = (unsigned short)run; sru[258 + lane * 4] = run;
        dinvs[lane * 4 + 2] = rsqrtf((float)(b2v + 1)); run += b2v;
        Rl[lane * 4 + 3] = (unsigned short)run; sru[259 + lane * 4] = run;
        dinvs[lane * 4 + 3] = rsqrtf((float)(b3 + 1));
        if (lane == 63) Rl[256] = (unsigned short)inc;
    }
    __syncthreads();                                      // B3

    // ---- P0d: scatter -> El (dst-sorted src locals)
    for (int i = t; i < ecnt; i += TPB) {
        unsigned short v = EPa[i];
        unsigned p = atomicAdd(&sru[256 + (v >> 8)], 1u);
        if (p < ECAP2) El[p] = (unsigned char)(v & 255);
    }
    __syncthreads();                                      // B4

    // ---- P1: t<256 builds M(h0) (2 thr/row); t>=256 lin1 -> G1T
    if (t < 256) {
        int dl = t >> 1, q = t & 1;
        int d = dl;
        float did = dinvs[d];
        if ((d >> 7) == q)
            *(unsigned short*)(Ms + dl * 512 + (((d >> 3) ^ (d & 15)) * 16) + (d & 7) * 2)
                = f2bbits(did * did);
        int r0 = Rl[d], r1 = Rl[d + 1];
        for (int e = r0; e < r1; ++e) {
            int s = El[e];
            if ((s >> 7) == q) {
                unsigned short* p =
                    (unsigned short*)(Ms + dl * 512 + (((s >> 3) ^ (d & 15)) * 16) + (s & 7) * 2);
                *p = f2bbits(bfbits(*p) + did * dinvs[s]);
            }
        }
    } else {
        int n = t - 256;
        float xv[NFEAT];
#pragma unroll
        for (int k = 0; k < NFEAT; k++) xv[k] = xsf[n * NFEAT + k];
#pragma unroll 4
        for (int c = 0; c < 32; c++) {
            float acc = 0.f;
#pragma unroll
            for (int k = 0; k < NFEAT; k++) acc += xv[k] * W1s[k * 32 + c];
            G1T[c * 266 + n] = f2bbits(acc);
        }
    }
    __syncthreads();                                      // B5

    // ---- P2: agg1(h0) -> H1T nodes 0..127
    {
        f32x4 acc[2] = {};
        for (int kt = 0; kt < 8; ++kt) {
            short8 af = *(const short8*)(Ms + (wvid * 16 + m) * 512 + (((kt * 4 + quad) ^ m) * 16));
            short8 bf0 = *(const short8*)(BufA + (size_t)m * 532 + kt * 64 + quad * 16);
            short8 bf1 = *(const short8*)(BufA + (size_t)(16 + m) * 532 + kt * 64 + quad * 16);
            acc[0] = __builtin_amdgcn_mfma_f32_16x16x32_bf16(af, bf0, acc[0], 0, 0, 0);
            acc[1] = __builtin_amdgcn_mfma_f32_16x16x32_bf16(af, bf1, acc[1], 0, 0, 0);
        }
#pragma unroll
        for (int ni = 0; ni < 2; ++ni) {
            int ch = ni * 16 + m;
            float bb = b1s[ch];
#pragma unroll
            for (int r = 0; r < 4; ++r) {
                int node = wvid * 16 + quad * 4 + r;
                H1T[ch * 266 + node] = f2bbits(fmaxf(acc[ni][r] + bb, 0.f));
            }
        }
    }
    __syncthreads();                                      // B6

    // ---- P3: zero Ms (linear); build M(h1) (4 thr/row)
    {
        uint4* mz = (uint4*)Ms;
        uint4 z = {0u, 0u, 0u, 0u};
        for (int i = t; i < 4096; i += TPB) mz[i] = z;
    }
    __syncthreads();                                      // B7
    {
        int dl = t >> 2, q = t & 3;
        int d = 128 + dl;
        float did = dinvs[d];
        if (((d & 255) >> 6) == q) {
            int sd = d & 255;
            *(unsigned short*)(Ms + dl * 512 + (((sd >> 3) ^ (d & 15)) * 16) + (sd & 7) * 2)
                = f2bbits(did * did);
        }
        int r0 = Rl[d], r1 = Rl[d + 1];
        for (int e = r0; e < r1; ++e) {
            int s = El[e];
            if ((s >> 6) == q) {
                unsigned short* p =
                    (unsigned short*)(Ms + dl * 512 + (((s >> 3) ^ (d & 15)) * 16) + (s & 7) * 2);
                *p = f2bbits(bfbits(*p) + did * dinvs[s]);
            }
        }
    }
    __syncthreads();                                      // B8

    // ---- P4: agg1(h1) -> H1T nodes 128..255
    {
        f32x4 acc[2] = {};
        for (int kt = 0; kt < 8; ++kt) {
            short8 af = *(const short8*)(Ms + (wvid * 16 + m) * 512 + (((kt * 4 + quad) ^ m) * 16));
            short8 bf0 = *(const short8*)(BufA + (size_t)m * 532 + kt * 64 + quad * 16);
            short8 bf1 = *(const short8*)(BufA + (size_t)(16 + m) * 532 + kt * 64 + quad * 16);
            acc[0] = __builtin_amdgcn_mfma_f32_16x16x32_bf16(af, bf0, acc[0], 0, 0, 0);
            acc[1] = __builtin_amdgcn_mfma_f32_16x16x32_bf16(af, bf1, acc[1], 0, 0, 0);
        }
#pragma unroll
        for (int ni = 0; ni < 2; ++ni) {
            int ch = ni * 16 + m;
            float bb = b1s[ch];
#pragma unroll
            for (int r = 0; r < 4; ++r) {
                int node = 128 + wvid * 16 + quad * 4 + r;
                H1T[ch * 266 + node] = f2bbits(fmaxf(acc[ni][r] + bb, 0.f));
            }
        }
    }
    __syncthreads();                                      // B9

    // ---- P5: fc1 stage (over G1T) + agg2'(h1) -> S2 rows 128..255
    for (int i = t; i < 8192; i += TPB) fc1s16[i] = f2bbits(fc1W[i]);
    {
        f32x4 acc[2] = {};
        for (int kt = 0; kt < 8; ++kt) {
            short8 af = *(const short8*)(Ms + (wvid * 16 + m) * 512 + (((kt * 4 + quad) ^ m) * 16));
            short8 bf0 = *(const short8*)(BufB + (size_t)m * 532 + kt * 64 + quad * 16);
            short8 bf1 = *(const short8*)(BufB + (size_t)(16 + m) * 532 + kt * 64 + quad * 16);
            acc[0] = __builtin_amdgcn_mfma_f32_16x16x32_bf16(af, bf0, acc[0], 0, 0, 0);
            acc[1] = __builtin_amdgcn_mfma_f32_16x16x32_bf16(af, bf1, acc[1], 0, 0, 0);
        }
#pragma unroll
        for (int ni = 0; ni < 2; ++ni) {
            int ch = ni * 16 + m;
#pragma unroll
            for (int r = 0; r < 4; ++r) {
                int node = 128 + wvid * 16 + quad * 4 + r;
                S2[node * 38 + ch] = f2bbits(acc[ni][r]);
            }
        }
    }
    __syncthreads();                                      // B10

    // ---- P6: zero Ms; rebuild M(h0) (4 thr/row)
    {
        uint4* mz = (uint4*)Ms;
        uint4 z = {0u, 0u, 0u, 0u};
        for (int i = t; i < 4096; i += TPB) mz[i] = z;
    }
    __syncthreads();                                      // B11
    {
        int dl = t >> 2, q = t & 3;
        int d = dl;
        float did = dinvs[d];
        if ((d >> 6) == q)
            *(unsigned short*)(Ms + dl * 512 + (((d >> 3) ^ (d & 15)) * 16) + (d & 7) * 2)
                = f2bbits(did * did);
        int r0 = Rl[d], r1 = Rl[d + 1];
        for (int e = r0; e < r1; ++e) {
            int s = El[e];
            if ((s >> 6) == q) {
                unsigned short* p =
                    (unsigned short*)(Ms + dl * 512 + (((s >> 3) ^ (d & 15)) * 16) + (s & 7) * 2);
                *p = f2bbits(bfbits(*p) + did * dinvs[s]);
            }
        }
    }
    __syncthreads();                                      // B12

    // ---- P7: agg2'(h0) -> S2 rows 0..127
    {
        f32x4 acc[2] = {};
        for (int kt = 0; kt < 8; ++kt) {
            short8 af = *(const short8*)(Ms + (wvid * 16 + m) * 512 + (((kt * 4 + quad) ^ m) * 16));
            short8 bf0 = *(const short8*)(BufB + (size_t)m * 532 + kt * 64 + quad * 16);
            short8 bf1 = *(const short8*)(BufB + (size_t)(16 + m) * 532 + kt * 64 + quad * 16);
            acc[0] = __builtin_amdgcn_mfma_f32_16x16x32_bf16(af, bf0, acc[0], 0, 0, 0);
            acc[1] = __builtin_amdgcn_mfma_f32_16x16x32_bf16(af, bf1, acc[1], 0, 0, 0);
        }
#pragma unroll
        for (int ni = 0; ni < 2; ++ni) {
            int ch = ni * 16 + m;
#pragma unroll
            for (int r = 0; r < 4; ++r) {
                int node = wvid * 16 + quad * 4 + r;
                S2[node * 38 + ch] = f2bbits(acc[ni][r]);
            }
        }
    }
    __syncthreads();                                      // B13

    // ---- P8: lin2 = relu(S2@W2+b2); pool + stations from accumulators
    {
#pragma unroll
        for (int mi = 0; mi < 2; ++mi) {
            int mt = wvid * 2 + mi;
            short8 af = *(const short8*)(BufC + (size_t)(mt * 16 + m) * 76 + quad * 16);
#pragma unroll
            for (int ni = 0; ni < 4; ++ni) {
                short8 bf = *(const short8*)((const unsigned char*)W2Ts + (size_t)(ni * 16 + m) * 80 + quad * 16);
                f32x4 c = {};
                c = __builtin_amdgcn_mfma_f32_16x16x32_bf16(af, bf, c, 0, 0, 0);
                int ch = ni * 16 + m;
                float bb = b2s[ch];
                float hv[4];
                float p = 0.f;
#pragma unroll
                for (int r = 0; r < 4; ++r) { hv[r] = fmaxf(c[r] + bb, 0.f); p += hv[r]; }
                p += __shfl_down(p, 32);
                p += __shfl_down(p, 16);
                if (quad == 0) atomicAdd(&poolf[ch], p);
#pragma unroll
                for (int r = 0; r < 4; ++r) {
                    int node = mt * 16 + quad * 4 + r;
                    int si = stmap[node];
                    if (si != 255) sts[si * 64 + ch] = hv[r];
                }
            }
        }
    }
    __syncthreads();                                      // B14

    // ---- P9: mean
    if (t < 64) meanf[t] = poolf[t] * (1.0f / 256.0f);
    __syncthreads();                                      // B15

    // ---- P10: MLP, one wave per station
    {
        int l = lane;
        int si = wvid;
        const float* st = sts + si * 64;
        float acc = 0.f;
#pragma unroll 8
        for (int k = 0; k < 64; k++) acc += st[k] * bfbits(fc1s16[k * 64 + l]);
#pragma unroll 8
        for (int k = 0; k < 64; k++) acc += meanf[k] * bfbits(fc1s16[(64 + k) * 64 + l]);
        float a = fmaxf(acc + fc1bs[l], 0.f) * fc2ws[l];
        for (int off = 32; off > 0; off >>= 1) a += __shfl_down(a, off);
        if (l == 0) out[g * 8 + si] = a + fc2bv;
    }
}

// ---- launch -----------------------------------------------------------------

extern "C" void kernel_launch(void* const* d_in, const int* in_sizes, int n_in,
                              void* d_out, int out_size, void* d_ws, size_t ws_size,
                              hipStream_t stream) {
    const float* x = (const float*)d_in[0];
    const int* ei = (const int*)d_in[1];
    const int* station_ids = (const int*)d_in[2];
    const float* W1 = (const float*)d_in[3];
    const float* b1 = (const float*)d_in[4];
    const float* W2 = (const float*)d_in[5];
    const float* bias2 = (const float*)d_in[6];
    const float* fc1W = (const float*)d_in[7];
    const float* fc1b = (const float*)d_in[8];
    const float* fc2W = (const float*)d_in[9];
    const float* fc2b = (const float*)d_in[10];
    float* out = (float*)d_out;
    (void)in_sizes; (void)n_in; (void)out_size; (void)ws_size;

    char* ws = (char*)d_ws;
    int* gcur = (int*)ws;                                     // 4 KiB (ends as per-graph count)
    unsigned short* gout = (unsigned short*)(ws + 0x2000);    // 1024*2560*2 = 5.24 MB

    const int* esrc = ei;
    const int* edst = ei + NEDGES;

    hipMemsetAsync(gcur, 0, NGRAPHS * sizeof(int), stream);
    k_gsort<<<NTILES, 1024, 0, stream>>>(esrc, edst, gcur, gout);
    k_fused<<<NGRAPHS, TPB, 0, stream>>>(x, station_ids, W1, b1, W2, bias2,
                                         fc1W, fc1b, fc2W, fc2b, gcur, gout, out);
}

// Round 12
// 200.120 us; speedup vs baseline: 1.1963x; 1.0501x over previous
//
#include <hip/hip_runtime.h>
#include <hip/hip_bf16.h>

// GraphQNetwork: 2x GCNConv (9->32->64, relu) + global mean pool + station MLP.
// Round 11: (a) gsort at 256 blocks x 8192 edges — all 256 CUs (was 64);
// (b) fused at 1024 thr with the 15-barrier r10 body: 8thr/row M-builds,
// one MFMA tile per wave, lin1 || M(h0)-build. Dense bucket format kept.

#define NNODES 262144
#define NPG 256
#define NGRAPHS 1024
#define NEDGES 2097152
#define NFEAT 9
#define ECAP2 2560           // per-graph bucket capacity (mean 2048, sd ~45)
#define T_EDGES 8192
#define NTILES (NEDGES / T_EDGES)   // 256
#define TPB 1024

typedef __hip_bfloat16 bf16;
typedef short short8 __attribute__((ext_vector_type(8)));
typedef float f32x4 __attribute__((ext_vector_type(4)));

__device__ __forceinline__ float bfbits(unsigned short u) { return __uint_as_float(((unsigned)u) << 16); }
__device__ __forceinline__ unsigned short f2bbits(float v) { bf16 b = __float2bfloat16(v); return *(unsigned short*)&b; }

// ---- edge partition: 256 tiles, dense buckets -------------------------------

__global__ void __launch_bounds__(1024) k_gsort(const int* __restrict__ src,
                                                const int* __restrict__ dst,
                                                int* __restrict__ gcur,
                                                unsigned short* __restrict__ gout) {
    __shared__ unsigned short edg[T_EDGES];   // graph id per staged edge
    __shared__ unsigned short pay[T_EDGES];   // d8<<8 | s8
    __shared__ int cnt[NGRAPHS];              // hist -> cursor
    __shared__ int goff[NGRAPHS];             // reserved global run base
    int t = threadIdx.x;
    int base = blockIdx.x * T_EDGES;
    cnt[t] = 0;
    __syncthreads();
    const int4* s4 = (const int4*)(src + base);
    const int4* d4 = (const int4*)(dst + base);
#pragma unroll
    for (int k = 0; k < T_EDGES / 4096; ++k) {
        int idx = k * 1024 + t;
        int4 dv = d4[idx];
        int4 sv = s4[idx];
        int i0 = idx * 4;
        edg[i0]     = (unsigned short)(dv.x >> 8);
        edg[i0 + 1] = (unsigned short)(dv.y >> 8);
        edg[i0 + 2] = (unsigned short)(dv.z >> 8);
        edg[i0 + 3] = (unsigned short)(dv.w >> 8);
        pay[i0]     = (unsigned short)(((dv.x & 255) << 8) | (sv.x & 255));
        pay[i0 + 1] = (unsigned short)(((dv.y & 255) << 8) | (sv.y & 255));
        pay[i0 + 2] = (unsigned short)(((dv.z & 255) << 8) | (sv.z & 255));
        pay[i0 + 3] = (unsigned short)(((dv.w & 255) << 8) | (sv.w & 255));
        atomicAdd(&cnt[dv.x >> 8], 1);
        atomicAdd(&cnt[dv.y >> 8], 1);
        atomicAdd(&cnt[dv.z >> 8], 1);
        atomicAdd(&cnt[dv.w >> 8], 1);
    }
    __syncthreads();
    {   // reserve one dense run per (block, graph); cnt becomes cursor
        int c = cnt[t];
        goff[t] = c ? atomicAdd(&gcur[t], c) : 0;
        cnt[t] = 0;
    }
    __syncthreads();
#pragma unroll
    for (int k = 0; k < T_EDGES / 1024; ++k) {
        int i = k * 1024 + t;
        int g = edg[i];
        int pos = atomicAdd(&cnt[g], 1);
        int off = goff[g] + pos;
        if (off < ECAP2) gout[(size_t)g * ECAP2 + off] = pay[i];
    }
}

// ---- fused per-graph kernel -------------------------------------------------

__global__ void __launch_bounds__(TPB) k_fused(
    const float* __restrict__ x, const int* __restrict__ station_ids,
    const float* __restrict__ W1, const float* __restrict__ b1,
    const float* __restrict__ W2, const float* __restrict__ b2,
    const float* __restrict__ fc1W, const float* __restrict__ fc1b,
    const float* __restrict__ fc2W, const float* __restrict__ fc2b,
    const int* __restrict__ gcnt, const unsigned short* __restrict__ gedges,
    float* __restrict__ out) {

    __shared__ __align__(16) unsigned char Ms[65536];     // half-M: 128 x 512 B
    __shared__ __align__(16) unsigned char BufA[17024];   // G1T [32][266] -> fc1s16
    __shared__ __align__(16) unsigned char BufB[17024];   // H1T [32][266]
    __shared__ __align__(16) unsigned char BufC[19456];   // xsf(9216)+EPa(5120) -> S2 [256][38]
    __shared__ __align__(16) unsigned short W2Ts[64 * 40];
    __shared__ float W1s[288];
    __shared__ float dinvs[256];
    __shared__ unsigned short Rl[260];
    __shared__ unsigned char El[ECAP2];
    __shared__ unsigned int sru[512];
    __shared__ float sts[512];
    __shared__ float meanf[64];
    __shared__ float poolf[64];
    __shared__ unsigned char stmap[256];
    __shared__ float b1s[32], b2s[64], fc1bs[64], fc2ws[64];
    __shared__ int stids[8];
    __shared__ float fc2bv;

    int t = threadIdx.x;
    int g = blockIdx.x;
    int nbase = g * NPG;
    int lane = t & 63, wvid = t >> 6;                     // 16 waves
    int m = lane & 15, quad = lane >> 4;

    float* xsf = (float*)BufC;                            // [256][9] f32
    unsigned short* EPa = (unsigned short*)(BufC + 9216); // dense bucket, 2560 u16
    unsigned short* G1T = (unsigned short*)BufA;          // [32][266]
    unsigned short* H1T = (unsigned short*)BufB;          // [32][266]
    unsigned short* S2 = (unsigned short*)BufC;           // [256][38]
    unsigned short* fc1s16 = (unsigned short*)BufA;       // [128][64]

    // ---- P0: stage + zero Ms (linear)
    int ecnt = min(gcnt[g], ECAP2);
    {
        const uint4* gev = (const uint4*)(gedges + (size_t)g * ECAP2);
        uint4* epv = (uint4*)EPa;
        for (int i = t; i < ECAP2 / 8; i += TPB) epv[i] = gev[i];
    }
    const float* xg = x + (size_t)nbase * NFEAT;
    for (int i = t; i < NPG * NFEAT; i += TPB) xsf[i] = xg[i];
    for (int i = t; i < NFEAT * 32; i += TPB) W1s[i] = W1[i];
    for (int i = t; i < 2048; i += TPB)
        W2Ts[(i >> 5) * 40 + (i & 31)] = f2bbits(W2[(i & 31) * 64 + (i >> 5)]);
    if (t < 32) b1s[t] = b1[t];
    if (t < 64) { b2s[t] = b2[t]; fc1bs[t] = fc1b[t]; fc2ws[t] = fc2W[t]; poolf[t] = 0.f; }
    if (t < 8) stids[t] = station_ids[t];
    if (t == 0) fc2bv = fc2b[0];
    if (t < 256) { stmap[t] = 255; sru[t] = 0u; }
    {
        uint4* mz = (uint4*)Ms;
        uint4 z = {0u, 0u, 0u, 0u};
        for (int i = t; i < 4096; i += TPB) mz[i] = z;
    }
    __syncthreads();                                      // B1
    if (t < 8) stmap[stids[t] & 255] = (unsigned char)t;

    // ---- P0b: dst histogram over dense bucket
    for (int i = t; i < ecnt; i += TPB) atomicAdd(&sru[EPa[i] >> 8], 1u);
    __syncthreads();                                      // B2

    // ---- P0c: single-wave scan -> Rl, cursors, dinvs
    if (wvid == 0) {
        int b0 = sru[lane * 4], b1v = sru[lane * 4 + 1], b2v = sru[lane * 4 + 2], b3 = sru[lane * 4 + 3];
        int s = b0 + b1v + b2v + b3;
        int inc = s;
        for (int off = 1; off < 64; off <<= 1) {
            int y = __shfl_up(inc, off);
            if (lane >= off) inc += y;
        }
        int run = inc - s;
        Rl[lane * 4] = (unsigned short)run; sru[256 + lane * 4] = run;
        dinvs[lane * 4] = rsqrtf((float)(b0 + 1)); run += b0;
        Rl[lane * 4 + 1] = (unsigned short)run; sru[257 + lane * 4] = run;
        dinvs[lane * 4 + 1] = rsqrtf((float)(b1v + 1)); run += b1v;
        Rl[lane * 4 + 2] = (unsigned short)run; sru[258 + lane * 4] = run;
        dinvs[lane * 4 + 2] = rsqrtf((float)(b2v + 1)); run += b2v;
        Rl[lane * 4 + 3] = (unsigned short)run; sru[259 + lane * 4] = run;
        dinvs[lane * 4 + 3] = rsqrtf((float)(b3 + 1));
        if (lane == 63) Rl[256] = (unsigned short)inc;
    }
    __syncthreads();                                      // B3

    // ---- P0d: scatter -> El (dst-sorted src locals)
    for (int i = t; i < ecnt; i += TPB) {
        unsigned short v = EPa[i];
        unsigned p = atomicAdd(&sru[256 + (v >> 8)], 1u);
        if (p < ECAP2) El[p] = (unsigned char)(v & 255);
    }
    __syncthreads();                                      // B4

    // ---- P1: t<512 builds M(h0) (4 thr/row); t>=512 lin1 -> G1T
    if (t < 512) {
        int dl = t >> 2, q = t & 3;
        int d = dl;
        float did = dinvs[d];
        if ((d >> 6) == q)
            *(unsigned short*)(Ms + dl * 512 + (((d >> 3) ^ (d & 15)) * 16) + (d & 7) * 2)
                = f2bbits(did * did);
        int r0 = Rl[d], r1 = Rl[d + 1];
        for (int e = r0; e < r1; ++e) {
            int s = El[e];
            if ((s >> 6) == q) {
                unsigned short* p =
                    (unsigned short*)(Ms + dl * 512 + (((s >> 3) ^ (d & 15)) * 16) + (s & 7) * 2);
                *p = f2bbits(bfbits(*p) + did * dinvs[s]);
            }
        }
    } else {
        int idx = t - 512;
        int n = idx >> 1, half = idx & 1;
        float xv[NFEAT];
#pragma unroll
        for (int k = 0; k < NFEAT; k++) xv[k] = xsf[n * NFEAT + k];
#pragma unroll 4
        for (int ci = 0; ci < 16; ci++) {
            int c = half * 16 + ci;
            float acc = 0.f;
#pragma unroll
            for (int k = 0; k < NFEAT; k++) acc += xv[k] * W1s[k * 32 + c];
            G1T[c * 266 + n] = f2bbits(acc);
        }
    }
    __syncthreads();                                      // B5

    // ---- P2: agg1(h0) -> H1T nodes 0..127 (one 16x16 tile per wave)
    {
        int mt = wvid >> 1, nt = wvid & 1;
        f32x4 acc = {};
        for (int kt = 0; kt < 8; ++kt) {
            short8 af = *(const short8*)(Ms + (mt * 16 + m) * 512 + (((kt * 4 + quad) ^ m) * 16));
            short8 bf = *(const short8*)(BufA + (size_t)(nt * 16 + m) * 532 + kt * 64 + quad * 16);
            acc = __builtin_amdgcn_mfma_f32_16x16x32_bf16(af, bf, acc, 0, 0, 0);
        }
        int ch = nt * 16 + m;
        float bb = b1s[ch];
#pragma unroll
        for (int r = 0; r < 4; ++r) {
            int node = mt * 16 + quad * 4 + r;
            H1T[ch * 266 + node] = f2bbits(fmaxf(acc[r] + bb, 0.f));
        }
    }
    __syncthreads();                                      // B6

    // ---- P3: zero Ms (linear); build M(h1) (8 thr/row)
    {
        uint4* mz = (uint4*)Ms;
        uint4 z = {0u, 0u, 0u, 0u};
        for (int i = t; i < 4096; i += TPB) mz[i] = z;
    }
    __syncthreads();                                      // B7
    {
        int dl = t >> 3, q = t & 7;
        int d = 128 + dl;
        float did = dinvs[d];
        if (((d & 255) >> 5) == q) {
            int sd = d & 255;
            *(unsigned short*)(Ms + dl * 512 + (((sd >> 3) ^ (d & 15)) * 16) + (sd & 7) * 2)
                = f2bbits(did * did);
        }
        int r0 = Rl[d], r1 = Rl[d + 1];
        for (int e = r0; e < r1; ++e) {
            int s = El[e];
            if ((s >> 5) == q) {
                unsigned short* p =
                    (unsigned short*)(Ms + dl * 512 + (((s >> 3) ^ (d & 15)) * 16) + (s & 7) * 2);
                *p = f2bbits(bfbits(*p) + did * dinvs[s]);
            }
        }
    }
    __syncthreads();                                      // B8

    // ---- P4: agg1(h1) -> H1T nodes 128..255
    {
        int mt = wvid >> 1, nt = wvid & 1;
        f32x4 acc = {};
        for (int kt = 0; kt < 8; ++kt) {
            short8 af = *(const short8*)(Ms + (mt * 16 + m) * 512 + (((kt * 4 + quad) ^ m) * 16));
            short8 bf = *(const short8*)(BufA + (size_t)(nt * 16 + m) * 532 + kt * 64 + quad * 16);
            acc = __builtin_amdgcn_mfma_f32_16x16x32_bf16(af, bf, acc, 0, 0, 0);
        }
        int ch = nt * 16 + m;
        float bb = b1s[ch];
#pragma unroll
        for (int r = 0; r < 4; ++r) {
            int node = 128 + mt * 16 + quad * 4 + r;
            H1T[ch * 266 + node] = f2bbits(fmaxf(acc[r] + bb, 0.f));
        }
    }
    __syncthreads();                                      // B9

    // ---- P5: fc1 stage (over G1T) + agg2'(h1) -> S2 rows 128..255
    for (int i = t; i < 8192; i += TPB) fc1s16[i] = f2bbits(fc1W[i]);
    {
        int mt = wvid >> 1, nt = wvid & 1;
        f32x4 acc = {};
        for (int kt = 0; kt < 8; ++kt) {
            short8 af = *(const short8*)(Ms + (mt * 16 + m) * 512 + (((kt * 4 + quad) ^ m) * 16));
            short8 bf = *(const short8*)(BufB + (size_t)(nt * 16 + m) * 532 + kt * 64 + quad * 16);
            acc = __builtin_amdgcn_mfma_f32_16x16x32_bf16(af, bf, acc, 0, 0, 0);
        }
        int ch = nt * 16 + m;
#pragma unroll
        for (int r = 0; r < 4; ++r) {
            int node = 128 + mt * 16 + quad * 4 + r;
            S2[node * 38 + ch] = f2bbits(acc[r]);
        }
    }
    __syncthreads();                                      // B10

    // ---- P6: zero Ms; rebuild M(h0) (8 thr/row)
    {
        uint4* mz = (uint4*)Ms;
        uint4 z = {0u, 0u, 0u, 0u};
        for (int i = t; i < 4096; i += TPB) mz[i] = z;
    }
    __syncthreads();                                      // B11
    {
        int dl = t >> 3, q = t & 7;
        int d = dl;
        float did = dinvs[d];
        if ((d >> 5) == q)
            *(unsigned short*)(Ms + dl * 512 + (((d >> 3) ^ (d & 15)) * 16) + (d & 7) * 2)
                = f2bbits(did * did);
        int r0 = Rl[d], r1 = Rl[d + 1];
        for (int e = r0; e < r1; ++e) {
            int s = El[e];
            if ((s >> 5) == q) {
                unsigned short* p =
                    (unsigned short*)(Ms + dl * 512 + (((s >> 3) ^ (d & 15)) * 16) + (s & 7) * 2);
                *p = f2bbits(bfbits(*p) + did * dinvs[s]);
            }
        }
    }
    __syncthreads();                                      // B12

    // ---- P7: agg2'(h0) -> S2 rows 0..127
    {
        int mt = wvid >> 1, nt = wvid & 1;
        f32x4 acc = {};
        for (int kt = 0; kt < 8; ++kt) {
            short8 af = *(const short8*)(Ms + (mt * 16 + m) * 512 + (((kt * 4 + quad) ^ m) * 16));
            short8 bf = *(const short8*)(BufB + (size_t)(nt * 16 + m) * 532 + kt * 64 + quad * 16);
            acc = __builtin_amdgcn_mfma_f32_16x16x32_bf16(af, bf, acc, 0, 0, 0);
        }
        int ch = nt * 16 + m;
#pragma unroll
        for (int r = 0; r < 4; ++r) {
            int node = mt * 16 + quad * 4 + r;
            S2[node * 38 + ch] = f2bbits(acc[r]);
        }
    }
    __syncthreads();                                      // B13

    // ---- P8: lin2 = relu(S2@W2+b2); pool + stations from accumulators
    {
        int mt = wvid;                                    // 16 waves x 16 rows
        short8 af = *(const short8*)(BufC + (size_t)(mt * 16 + m) * 76 + quad * 16);
#pragma unroll
        for (int ni = 0; ni < 4; ++ni) {
            short8 bf = *(const short8*)((const unsigned char*)W2Ts + (size_t)(ni * 16 + m) * 80 + quad * 16);
            f32x4 c = {};
            c = __builtin_amdgcn_mfma_f32_16x16x32_bf16(af, bf, c, 0, 0, 0);
            int ch = ni * 16 + m;
            float bb = b2s[ch];
            float hv[4];
            float p = 0.f;
#pragma unroll
            for (int r = 0; r < 4; ++r) { hv[r] = fmaxf(c[r] + bb, 0.f); p += hv[r]; }
            p += __shfl_down(p, 32);
            p += __shfl_down(p, 16);
            if (quad == 0) atomicAdd(&poolf[ch], p);
#pragma unroll
            for (int r = 0; r < 4; ++r) {
                int node = mt * 16 + quad * 4 + r;
                int si = stmap[node];
                if (si != 255) sts[si * 64 + ch] = hv[r];
            }
        }
    }
    __syncthreads();                                      // B14

    // ---- P9: mean
    if (t < 64) meanf[t] = poolf[t] * (1.0f / 256.0f);
    __syncthreads();                                      // B15

    // ---- P10: MLP, one wave per station (waves 8..15 idle)
    if (wvid < 8) {
        int l = lane;
        int si = wvid;
        const float* st = sts + si * 64;
        float acc = 0.f;
#pragma unroll 8
        for (int k = 0; k < 64; k++) acc += st[k] * bfbits(fc1s16[k * 64 + l]);
#pragma unroll 8
        for (int k = 0; k < 64; k++) acc += meanf[k] * bfbits(fc1s16[(64 + k) * 64 + l]);
        float a = fmaxf(acc + fc1bs[l], 0.f) * fc2ws[l];
        for (int off = 32; off > 0; off >>= 1) a += __shfl_down(a, off);
        if (l == 0) out[g * 8 + si] = a + fc2bv;
    }
}

// ---- launch -----------------------------------------------------------------

extern "C" void kernel_launch(void* const* d_in, const int* in_sizes, int n_in,
                              void* d_out, int out_size, void* d_ws, size_t ws_size,
                              hipStream_t stream) {
    const float* x = (const float*)d_in[0];
    const int* ei = (const int*)d_in[1];
    const int* station_ids = (const int*)d_in[2];
    const float* W1 = (const float*)d_in[3];
    const float* b1 = (const float*)d_in[4];
    const float* W2 = (const float*)d_in[5];
    const float* bias2 = (const float*)d_in[6];
    const float* fc1W = (const float*)d_in[7];
    const float* fc1b = (const float*)d_in[8];
    const float* fc2W = (const float*)d_in[9];
    const float* fc2b = (const float*)d_in[10];
    float* out = (float*)d_out;
    (void)in_sizes; (void)n_in; (void)out_size; (void)ws_size;

    char* ws = (char*)d_ws;
    int* gcur = (int*)ws;                                     // 4 KiB (ends as per-graph count)
    unsigned short* gout = (unsigned short*)(ws + 0x2000);    // 1024*2560*2 = 5.24 MB

    const int* esrc = ei;
    const int* edst = ei + NEDGES;

    hipMemsetAsync(gcur, 0, NGRAPHS * sizeof(int), stream);
    k_gsort<<<NTILES, 1024, 0, stream>>>(esrc, edst, gcur, gout);
    k_fused<<<NGRAPHS, TPB, 0, stream>>>(x, station_ids, W1, b1, W2, bias2,
                                         fc1W, fc1b, fc2W, fc2b, gcur, gout, out);
}